// Round 13
// baseline (290.194 us; speedup 1.0000x reference)
//
#include <hip/hip_runtime.h>
#include <hip/hip_bf16.h>
#include <cstdint>
#include <cstddef>

// Problem constants
#define Bq  4
#define Nq  2048
#define Mq  256
#define Dq  1024
#define CDq 768
#define Hq  8
#define DHq 64
#define Jq  2305   // Mq + 1 + Nq
#define QKVN 640   // H*DH + 2*DH (fused q+kv projection width)
#define NCH 37     // ceil(Jq/64)
#define J2  (NCH * 64)   // 2368 padded

typedef __bf16  bf16x8 __attribute__((ext_vector_type(8)));
typedef float   f32x4  __attribute__((ext_vector_type(4)));
typedef float   f32x4u __attribute__((ext_vector_type(4), aligned(4)));
typedef float   f32x16 __attribute__((ext_vector_type(16)));
typedef short   s16x8  __attribute__((ext_vector_type(8)));
typedef short   s16x4  __attribute__((ext_vector_type(4)));
typedef unsigned int u32x4 __attribute__((ext_vector_type(4)));
typedef unsigned short u16;
typedef unsigned int   u32;

__device__ __forceinline__ u16 f2b(float v) {          // f32 -> bf16 (RNE)
  unsigned x = __builtin_bit_cast(unsigned, v);
  unsigned r = (x + 0x7fffu + ((x >> 16) & 1u)) >> 16;
  return (u16)r;
}
__device__ __forceinline__ float b2f(u16 u) {
  unsigned x = ((unsigned)u) << 16;
  return __builtin_bit_cast(float, x);
}
// pack two f32 -> one u32 of 2xbf16 (lo -> bits[15:0]), RNE
__device__ __forceinline__ u32 cvtpk(float lo, float hi) {
  u32 r;
  asm("v_cvt_pk_bf16_f32 %0, %1, %2" : "=v"(r) : "v"(lo), "v"(hi));
  return r;
}
// swap lanes[32:63] of a with lanes[0:31] of b (gfx950)
__device__ __forceinline__ void pswap(u32& a, u32& b) {
  asm volatile("v_permlane32_swap_b32 %0, %1" : "+v"(a), "+v"(b));
}
__device__ __forceinline__ f32x4 mfma16(bf16x8 a, bf16x8 b, f32x4 c) {
  return __builtin_amdgcn_mfma_f32_16x16x32_bf16(a, b, c, 0, 0, 0);
}
__device__ __forceinline__ f32x16 mfma32(bf16x8 a, bf16x8 b, f32x16 c) {
  return __builtin_amdgcn_mfma_f32_32x32x16_bf16(a, b, c, 0, 0, 0);
}
__device__ __forceinline__ bf16x8 frag_ld(const u16* p) {
  return __builtin_bit_cast(bf16x8, *(const s16x8*)p);
}
__device__ __forceinline__ void stout(float* p, float v) { *p = v; }
__device__ __forceinline__ void stout(u16*   p, float v) { *p = f2b(v); }

// async global->LDS, 16B per lane. ldsDst is wave-uniform base.
__device__ __forceinline__ void gl_lds16(const void* gSrc, void* ldsDst) {
  __builtin_amdgcn_global_load_lds(
      (const __attribute__((address_space(1))) void*)gSrc,
      (__attribute__((address_space(3))) void*)ldsDst, 16, 0, 0);
}

// ------- merged prep: input LayerNorms (bf16 out) + weight transposes -------
__global__ __launch_bounds__(256) void prep_kernel(
    const float* __restrict__ x,   const float* __restrict__ ln_g,
    const float* __restrict__ ln_b, u16* __restrict__ xn,
    const float* __restrict__ ctx, const float* __restrict__ cln_g,
    const float* __restrict__ cln_b, u16* __restrict__ ctxn,
    const float* __restrict__ Wq, const float* __restrict__ Wkv,
    const float* __restrict__ Wc, const float* __restrict__ Wo,
    u16* __restrict__ WqkvT, u16* __restrict__ WcT, u16* __restrict__ WoT) {
  const int tid = threadIdx.x;
  if (blockIdx.x < Bq * Nq + Bq * Mq) {
    const int row = blockIdx.x;
    const float* in; const float* g; const float* bb; u16* out; int D;
    if (row < Bq * Nq) {
      in = x + (size_t)row * Dq; g = ln_g; bb = ln_b;
      out = xn + (size_t)row * Dq; D = Dq;
    } else {
      int r2 = row - Bq * Nq;
      in = ctx + (size_t)r2 * CDq; g = cln_g; bb = cln_b;
      out = ctxn + (size_t)r2 * CDq; D = CDq;
    }
    __shared__ float buf[1024];
    __shared__ float red[8];
    float s = 0.f, s2 = 0.f;
    for (int i = tid; i < D; i += 256) {
      float v = in[i];
      buf[i] = v;
      s += v; s2 += v * v;
    }
    #pragma unroll
    for (int off = 32; off; off >>= 1) {
      s  += __shfl_down(s,  off);
      s2 += __shfl_down(s2, off);
    }
    if ((tid & 63) == 0) { red[tid >> 6] = s; red[4 + (tid >> 6)] = s2; }
    __syncthreads();
    float sum = red[0] + red[1] + red[2] + red[3];
    float sq  = red[4] + red[5] + red[6] + red[7];
    float mean = sum / D;
    float var  = sq / D - mean * mean;
    float rstd = rsqrtf(var + 1e-5f);
    for (int i = tid; i < D; i += 256)
      out[i] = f2b((buf[i] - mean) * rstd * g[i] + bb[i]);
  } else {
    __shared__ float T[32][33];
    int bid = blockIdx.x - (Bq * Nq + Bq * Mq);
    const float* W; u16* WT; int K, N, bx, by;
    if (bid < 512)      { W = Wq;  WT = WqkvT;                    K = 1024; N = 512;  bx = bid % 16;        by = bid / 16; }
    else if (bid < 640) { W = Wkv; WT = WqkvT + (size_t)512*1024; K = 1024; N = 128;  bx = (bid-512) % 4;   by = (bid-512) / 4; }
    else if (bid < 736) { W = Wc;  WT = WcT;                      K = 768;  N = 128;  bx = (bid-640) % 4;   by = (bid-640) / 4; }
    else                { W = Wo;  WT = WoT;                      K = 512;  N = 1024; bx = (bid-736) % 32;  by = (bid-736) / 32; }
    const int n0 = bx * 32, k0 = by * 32;
    const int tx = tid & 31, ty = tid >> 5;
    #pragma unroll
    for (int i = 0; i < 32; i += 8)
      T[ty + i][tx] = W[(size_t)(k0 + ty + i) * N + n0 + tx];
    __syncthreads();
    #pragma unroll
    for (int i = 0; i < 32; i += 8)
      WT[(size_t)(n0 + ty + i) * K + k0 + tx] = f2b(T[tx][ty + i]);
  }
}

// ---------------- final LayerNorm (bf16 in, fp32 out) ----------------
__global__ __launch_bounds__(256) void ln_out_kernel(
    const u16* __restrict__ in, const float* __restrict__ g,
    const float* __restrict__ bb, float* __restrict__ out) {
  const int row = blockIdx.x;
  const int tid = threadIdx.x;
  __shared__ float buf[1024];
  __shared__ float red[8];
  const u16* xr = in + (size_t)row * Dq;
  float s = 0.f, s2 = 0.f;
  {
    s16x4 v4 = *(const s16x4*)(xr + tid * 4);
    #pragma unroll
    for (int e = 0; e < 4; ++e) {
      float v = b2f((u16)v4[e]);
      buf[tid * 4 + e] = v;
      s += v; s2 += v * v;
    }
  }
  #pragma unroll
  for (int off = 32; off; off >>= 1) {
    s  += __shfl_down(s,  off);
    s2 += __shfl_down(s2, off);
  }
  if ((tid & 63) == 0) { red[tid >> 6] = s; red[4 + (tid >> 6)] = s2; }
  __syncthreads();
  float sum = red[0] + red[1] + red[2] + red[3];
  float sq  = red[4] + red[5] + red[6] + red[7];
  float mean = sum / Dq;
  float var  = sq / Dq - mean * mean;
  float rstd = rsqrtf(var + 1e-5f);
  #pragma unroll
  for (int e = 0; e < 4; ++e) {
    int i = tid * 4 + e;
    out[(size_t)row * Dq + i] = (buf[i] - mean) * rstd * g[i] + bb[i];
  }
}

// ---------- GEMM body (m97 structure), shared by both GEMM kernels ----------
template <typename OT>
__device__ __forceinline__ void gemm_body(const u16* __restrict__ A,
                                          const u16* __restrict__ BT,
                                          OT* __restrict__ C,
                                          int N, int K, int m0, int n0,
                                          u16* Al, u16* Bl) {
  const int tid  = threadIdx.x;
  const int lane = tid & 63, wave = tid >> 6;
  const int l16  = lane & 15, lhi = lane >> 4;
  const int wm = (wave >> 1) * 64, wn = (wave & 1) * 64;

  const int offB = (wave << 10) + (lane << 4);
  const int srow = offB >> 6;
  const int scby = offB & 63;

  f32x4 acc[4][4];
  #pragma unroll
  for (int i = 0; i < 4; ++i)
    #pragma unroll
    for (int j = 0; j < 4; ++j) acc[i][j] = f32x4{0.f, 0.f, 0.f, 0.f};

  for (int k0 = 0; k0 < K; k0 += 32) {
    __syncthreads();
    #pragma unroll
    for (int c = 0; c < 2; ++c) {
      gl_lds16((const char*)(A  + (size_t)(m0 + srow + c * 64) * K + k0) + scby,
               (char*)Al + c * 4096 + (wave << 10));
      gl_lds16((const char*)(BT + (size_t)(n0 + srow + c * 64) * K + k0) + scby,
               (char*)Bl + c * 4096 + (wave << 10));
    }
    __syncthreads();

    bf16x8 af[4], bfr[4];
    #pragma unroll
    for (int mt = 0; mt < 4; ++mt)
      af[mt] = frag_ld(Al + (wm + mt * 16 + l16) * 32 + lhi * 8);
    #pragma unroll
    for (int nt = 0; nt < 4; ++nt)
      bfr[nt] = frag_ld(Bl + (wn + nt * 16 + l16) * 32 + lhi * 8);
    __builtin_amdgcn_s_setprio(1);
    #pragma unroll
    for (int mt = 0; mt < 4; ++mt)
      #pragma unroll
      for (int nt = 0; nt < 4; ++nt)
        acc[mt][nt] = mfma16(af[mt], bfr[nt], acc[mt][nt]);
    __builtin_amdgcn_s_setprio(0);
  }

  #pragma unroll
  for (int mt = 0; mt < 4; ++mt)
    #pragma unroll
    for (int nt = 0; nt < 4; ++nt)
      #pragma unroll
      for (int r = 0; r < 4; ++r)
        stout(C + (size_t)(m0 + wm + mt * 16 + lhi * 4 + r) * N
                + (n0 + wn + nt * 16 + l16),
              acc[mt][nt][r]);
}

// qkv GEMM (y<5) with ckv GEMM folded in as grid row y==5 (8 blocks active)
__global__ __launch_bounds__(256) void gemm_qkv_ckv(
    const u16* __restrict__ xn, const u16* __restrict__ WqkvT,
    u16* __restrict__ qkv,
    const u16* __restrict__ ctxn, const u16* __restrict__ WcT,
    u16* __restrict__ ckvb) {
  const u16 *A, *BT; u16* C; int N, K, m0, n0;
  if (blockIdx.y < 5) {
    A = xn; BT = WqkvT; C = qkv; N = QKVN; K = Dq;
    m0 = blockIdx.x * 128; n0 = blockIdx.y * 128;
  } else {
    if (blockIdx.x >= 8) return;
    A = ctxn; BT = WcT; C = ckvb; N = 2 * DHq; K = CDq;
    m0 = blockIdx.x * 128; n0 = 0;
  }
  __shared__ __align__(16) u16 Al[128 * 32];
  __shared__ __align__(16) u16 Bl[128 * 32];
  gemm_body<u16>(A, BT, C, N, K, m0, n0, Al, Bl);
}

// output projection GEMM (bf16 C = y)
__global__ __launch_bounds__(256) void gemm128b(const u16* __restrict__ A,
                                                const u16* __restrict__ BT,
                                                u16* __restrict__ C,
                                                int N, int K) {
  __shared__ __align__(16) u16 Al[128 * 32];
  __shared__ __align__(16) u16 Bl[128 * 32];
  gemm_body<u16>(A, BT, C, N, K, blockIdx.x * 128, blockIdx.y * 128, Al, Bl);
}

// ------- build tiled+swizzled K / V^T (per (b,chunk): 64x64 bf16 tile) ------
// K tile byte  = row*128 + ((d*2)   ^ ((row&7)<<4))   [row = j within chunk]
// VT tile byte = d*128   + ((row*2) ^ ((d&7)<<4))
__global__ void build_kv(const u16* __restrict__ qkv,   // (B*N,640) bf16
                         const u16* __restrict__ ckvb,  // (B*M,128) bf16
                         const float* __restrict__ nullkv, // (2,64) f32
                         const float* __restrict__ bc,     // (128,) f32
                         u16* __restrict__ Kt, u16* __restrict__ Vt) {
  int idx = blockIdx.x * 256 + threadIdx.x;
  if (idx >= Bq * J2 * 64) return;
  int d = idx & 63;
  int t = idx >> 6;
  int j = t % J2;
  int b = t / J2;
  float k = 0.f, v = 0.f;
  if (j < Mq) {
    const u16* p = ckvb + (size_t)(b * Mq + j) * 128;
    k = b2f(p[d])      + bc[d];
    v = b2f(p[64 + d]) + bc[64 + d];
  } else if (j == Mq) {
    k = nullkv[d];
    v = nullkv[64 + d];
  } else if (j < Jq) {
    const u16* p = qkv + (size_t)(b * Nq + (j - Mq - 1)) * QKVN + 512;
    k = b2f(p[d]);
    v = b2f(p[64 + d]);
  }
  int ch = j >> 6, row = j & 63;
  char* tbase = (char*)Kt + ((size_t)(b * NCH + ch)) * 8192;
  *(u16*)(tbase + row * 128 + ((d << 1) ^ ((row & 7) << 4))) = f2b(k);
  char* vbase = (char*)Vt + ((size_t)(b * NCH + ch)) * 8192;
  *(u16*)(vbase + d * 128 + ((row << 1) ^ ((d & 7) << 4))) = f2b(v);
}

// --- attention: 32x32 swapped-MFMA, PER-WAVE staging, ZERO barriers ---------
// grid (N/64, H, B) = (32,8,4), block 128 = 2 waves; each wave owns 32 q-rows
// and stages its OWN K/V tiles into a private LDS region. No __syncthreads in
// the loop: per chunk, issue next stage (16 gl_lds) + next bias (8 loads),
// then s_waitcnt vmcnt(24) -- the 24 just-issued stay in flight, the prior
// chunk's have completed. Waves never gate on each other's HBM latency tails.
__global__ __launch_bounds__(128) void attn_kernel(
    const u16* __restrict__ qkv, const u16* __restrict__ Kt,
    const u16* __restrict__ Vt, const float* __restrict__ bias,
    u16* __restrict__ att) {
  __shared__ __align__(16) u16 Kl [2][2][4096];   // [wave][buf][8KB]
  __shared__ __align__(16) u16 VTl[2][2][4096];
  const int tid  = threadIdx.x;
  const int wave = tid >> 6, lane = tid & 63;
  const int l = lane & 31, hi = lane >> 5;
  const int qt = blockIdx.x, h = blockIdx.y, b = blockIdx.z;
  const int qrow0 = qt * 64 + wave * 32;

  // Q B-frags: lane holds Q[q=qrow0+l][d = kt*16 + hi*8 + e], kt=0..3
  bf16x8 qf[4];
  {
    const u16* qp = qkv + ((size_t)(b * Nq + qrow0 + l)) * QKVN
                        + h * DHq + hi * 8;
    #pragma unroll
    for (int kt = 0; kt < 4; ++kt) qf[kt] = frag_ld(qp + kt * 16);
  }

  float m_s = -INFINITY, l_s = 0.f;
  f32x16 oacc[2];   // O[q=(r&3)+8(r>>2)+4hi][d = dt*32 + l]
  #pragma unroll
  for (int dt = 0; dt < 2; ++dt)
    #pragma unroll
    for (int r = 0; r < 16; ++r) oacc[dt][r] = 0.f;

  // bias row base for q = qrow0+l, plus the +4*hi column offset
  const float* bp = bias
      + ((size_t)((b * Hq + h) * (size_t)Nq + qrow0 + l)) * Jq + 4 * hi;

  const size_t tb0 = (size_t)b * NCH;
  const int soff = lane << 4;   // per-lane src byte offset within 1KB group

  auto stage = [&](int buf, int ch) {
    const char* kt_ = (const char*)Kt + (tb0 + ch) * 8192 + soff;
    const char* vt_ = (const char*)Vt + (tb0 + ch) * 8192 + soff;
    char* kl = (char*)&Kl[wave][buf][0];
    char* vl = (char*)&VTl[wave][buf][0];
    #pragma unroll
    for (int i = 0; i < 8; ++i) {
      gl_lds16(kt_ + i * 1024, kl + i * 1024);
      gl_lds16(vt_ + i * 1024, vl + i * 1024);
    }
  };

  // bias regs: bv[jt][g] = bias[q][jc + jt*32 + 8g + 4hi + (0..3)]
  auto loadBias = [&](f32x4 (&bv)[2][4], int ch) {
    const int jc = ch * 64;
    if (ch < NCH - 1) {
      #pragma unroll
      for (int jt = 0; jt < 2; ++jt)
        #pragma unroll
        for (int g = 0; g < 4; ++g)
          bv[jt][g] = (f32x4)(*(const f32x4u*)(bp + jc + jt * 32 + 8 * g));
    } else {
      #pragma unroll
      for (int jt = 0; jt < 2; ++jt)
        #pragma unroll
        for (int g = 0; g < 4; ++g)
          #pragma unroll
          for (int e = 0; e < 4; ++e) {
            int jg = jc + jt * 32 + 8 * g + 4 * hi + e;
            bv[jt][g][e] = (jg < Jq) ? bp[jc + jt * 32 + 8 * g + e] : -1e30f;
          }
    }
  };

  f32x4 bvA[2][4], bvB[2][4];
  stage(0, 0);
  loadBias(bvA, 0);

  auto body = [&](int ch, f32x4 (&bvC)[2][4], f32x4 (&bvN)[2][4]) {
    const int cur = ch & 1;
    if (ch + 1 < NCH) {
      stage(cur ^ 1, ch + 1);      // 16 VMEM
      loadBias(bvN, ch + 1);       //  8 VMEM
      asm volatile("s_waitcnt vmcnt(24)" ::: "memory");
    } else {
      asm volatile("s_waitcnt vmcnt(0)" ::: "memory");
    }
    __builtin_amdgcn_sched_barrier(0);

    const char* kbase = (const char*)&Kl[wave][cur][0];
    const char* vbase = (const char*)&VTl[wave][cur][0];

    // ---- S^T = K @ Q^T ----
    f32x16 sacc[2];
    #pragma unroll
    for (int jt = 0; jt < 2; ++jt)
      #pragma unroll
      for (int r = 0; r < 16; ++r) sacc[jt][r] = 0.f;
    __builtin_amdgcn_s_setprio(1);
    #pragma unroll
    for (int jt = 0; jt < 2; ++jt) {
      const int row = jt * 32 + l;
      const int sw = (row & 7) << 4;
      #pragma unroll
      for (int kt = 0; kt < 4; ++kt) {
        bf16x8 kf = frag_ld((const u16*)(kbase + row * 128
                                         + ((kt * 32 + hi * 16) ^ sw)));
        sacc[jt] = mfma32(kf, qf[kt], sacc[jt]);
      }
    }
    __builtin_amdgcn_s_setprio(0);

    // ---- scale + bias ----
    float sv[2][16];
    #pragma unroll
    for (int jt = 0; jt < 2; ++jt)
      #pragma unroll
      for (int r = 0; r < 16; ++r)
        sv[jt][r] = sacc[jt][r] * 0.125f + bvC[jt][r >> 2][r & 3];

    // ---- row max (q = l, dup across hi) ----
    float pmax = sv[0][0];
    #pragma unroll
    for (int jt = 0; jt < 2; ++jt)
      #pragma unroll
      for (int r = 0; r < 16; ++r) pmax = fmaxf(pmax, sv[jt][r]);
    pmax = fmaxf(pmax, __shfl_xor(pmax, 32));

    // ---- defer-max rescale ----
    if (__any(pmax > m_s + 8.f)) {
      float mnew = fmaxf(m_s, pmax);
      float corr = __expf(m_s - mnew);   // 0 on first chunk
      l_s *= corr;
      m_s = mnew;
      #pragma unroll
      for (int r = 0; r < 16; ++r) {
        float c = __shfl(corr, (r & 3) + 8 * (r >> 2) + 4 * hi);
        oacc[0][r] *= c;
        oacc[1][r] *= c;
      }
    }

    // ---- P = exp(S - m), row sum ----
    float ps = 0.f;
    #pragma unroll
    for (int jt = 0; jt < 2; ++jt)
      #pragma unroll
      for (int r = 0; r < 16; ++r) {
        float pv = __expf(sv[jt][r] - m_s);
        sv[jt][r] = pv;
        ps += pv;
      }
    ps += __shfl_xor(ps, 32);
    l_s += ps;

    // ---- pack P to bf16 pairs ----
    u32 pk[2][8];
    #pragma unroll
    for (int jt = 0; jt < 2; ++jt)
      #pragma unroll
      for (int g = 0; g < 4; ++g) {
        pk[jt][2 * g]     = cvtpk(sv[jt][4 * g],     sv[jt][4 * g + 1]);
        pk[jt][2 * g + 1] = cvtpk(sv[jt][4 * g + 2], sv[jt][4 * g + 3]);
      }

    // ---- PV: A-frag per kt via permlane32_swap; B = V^T frags ----
    #pragma unroll
    for (int kt = 0; kt < 4; ++kt) {
      const int t = kt & 1, js = kt >> 1;
      u32 a0 = pk[js][4 * t],     b0 = pk[js][4 * t + 2];
      u32 a1 = pk[js][4 * t + 1], b1 = pk[js][4 * t + 3];
      pswap(a0, b0);
      pswap(a1, b1);
      bf16x8 paf = __builtin_bit_cast(bf16x8, u32x4{a0, a1, b0, b1});
      __builtin_amdgcn_s_setprio(1);
      #pragma unroll
      for (int dt = 0; dt < 2; ++dt) {
        const int vrow = dt * 32 + l;
        bf16x8 vf = frag_ld((const u16*)(vbase + vrow * 128
                     + ((kt * 32 + hi * 16) ^ ((vrow & 7) << 4))));
        oacc[dt] = mfma32(paf, vf, oacc[dt]);
      }
      __builtin_amdgcn_s_setprio(0);
    }
  };

  int ch = 0;
  while (true) {
    body(ch, bvA, bvB);
    if (++ch == NCH) break;
    body(ch, bvB, bvA);
    if (++ch == NCH) break;
  }

  // ---- epilogue: 1/l broadcast from lane q to O-layout, store ----
  float linv = 1.0f / l_s;
  #pragma unroll
  for (int r = 0; r < 16; ++r) {
    const int qo = (r & 3) + 8 * (r >> 2) + 4 * hi;
    float inv = __shfl(linv, qo);
    u16* op = att + ((size_t)(b * Nq + qrow0 + qo)) * (Hq * DHq) + h * DHq + l;
    op[0]  = f2b(oacc[0][r] * inv);
    op[32] = f2b(oacc[1][r] * inv);
  }
}

// ---------------- host ----------------
extern "C" void kernel_launch(void* const* d_in, const int* in_sizes, int n_in,
                              void* d_out, int out_size, void* d_ws, size_t ws_size,
                              hipStream_t stream) {
  const float* x       = (const float*)d_in[0];
  const float* context = (const float*)d_in[1];
  const float* att_bias= (const float*)d_in[2];
  const float* ln_g    = (const float*)d_in[3];
  const float* ln_b    = (const float*)d_in[4];
  const float* null_kv = (const float*)d_in[5];
  const float* Wq      = (const float*)d_in[6];
  const float* Wkv     = (const float*)d_in[7];
  const float* cln_g   = (const float*)d_in[8];
  const float* cln_b   = (const float*)d_in[9];
  const float* Wc      = (const float*)d_in[10];
  const float* bc      = (const float*)d_in[11];
  const float* Wo      = (const float*)d_in[12];
  const float* oln_g   = (const float*)d_in[13];
  const float* oln_b   = (const float*)d_in[14];
  float* out = (float*)d_out;

  char* p = (char*)d_ws;
  auto alloc = [&](size_t bytes) {
    void* r = (void*)p;
    p += (bytes + 255) & ~(size_t)255;
    return r;
  };
  u16* xn     = (u16*)alloc((size_t)Bq * Nq * Dq * 2);
  u16* ctxn   = (u16*)alloc((size_t)Bq * Mq * CDq * 2);
  u16* WqkvT  = (u16*)alloc((size_t)QKVN * Dq * 2);       // [640][1024]
  u16* WcT    = (u16*)alloc((size_t)2 * DHq * CDq * 2);   // [128][768]
  u16* WoT    = (u16*)alloc((size_t)Dq * Hq * DHq * 2);   // [1024][512]
  u16* qkv    = (u16*)alloc((size_t)Bq * Nq * QKVN * 2);  // fused q|kv
  u16* ckvb   = (u16*)alloc((size_t)Bq * Mq * 2 * DHq * 2);
  u16* Ktil   = (u16*)alloc((size_t)Bq * NCH * 8192);
  u16* Vtil   = (u16*)alloc((size_t)Bq * NCH * 8192);
  u16* attb   = (u16*)alloc((size_t)Bq * Nq * Hq * DHq * 2);
  u16* y      = (u16*)alloc((size_t)Bq * Nq * Dq * 2);    // bf16 intermediate

  // 1. merged input LNs + weight transposes
  prep_kernel<<<Bq * Nq + Bq * Mq + 1248, 256, 0, stream>>>(
      x, ln_g, ln_b, xn, context, cln_g, cln_b, ctxn,
      Wq, Wkv, Wc, Wo, WqkvT, WcT, WoT);

  // 2. projections: fused q|kv GEMM with ckv GEMM folded in
  gemm_qkv_ckv<<<dim3(Bq * Nq / 128, 6), 256, 0, stream>>>(
      xn, WqkvT, qkv, ctxn, WcT, ckvb);

  // 3. concat K/V into swizzled 64-row tiles
  build_kv<<<(Bq * J2 * 64 + 255) / 256, 256, 0, stream>>>(
      qkv, ckvb, null_kv, bc, Ktil, Vtil);

  // 4. attention (wave-decoupled, barrier-free)
  attn_kernel<<<dim3(Nq / 64, Hq, Bq), 128, 0, stream>>>(
      qkv, Ktil, Vtil, att_bias, attb);

  // 5. output projection (bf16 y) + final LN
  gemm128b<<<dim3(Bq * Nq / 128, Dq / 128), 256, 0, stream>>>(
      attb, WoT, y, Dq, Hq * DHq);
  ln_out_kernel<<<Bq * Nq, 256, 0, stream>>>(y, oln_g, oln_b, out);
}

// Round 14
// 249.552 us; speedup vs baseline: 1.1629x; 1.1629x over previous
//
#include <hip/hip_runtime.h>
#include <hip/hip_bf16.h>
#include <cstdint>
#include <cstddef>

// Problem constants
#define Bq  4
#define Nq  2048
#define Mq  256
#define Dq  1024
#define CDq 768
#define Hq  8
#define DHq 64
#define Jq  2305   // Mq + 1 + Nq
#define QKVN 640   // H*DH + 2*DH (fused q+kv projection width)
#define NCH 37     // ceil(Jq/64)
#define J2  (NCH * 64)   // 2368 padded

typedef __bf16  bf16x8 __attribute__((ext_vector_type(8)));
typedef float   f32x4  __attribute__((ext_vector_type(4)));
typedef float   f32x4u __attribute__((ext_vector_type(4), aligned(4)));
typedef float   f32x16 __attribute__((ext_vector_type(16)));
typedef short   s16x8  __attribute__((ext_vector_type(8)));
typedef short   s16x4  __attribute__((ext_vector_type(4)));
typedef unsigned int u32x4 __attribute__((ext_vector_type(4)));
typedef unsigned short u16;
typedef unsigned int   u32;

__device__ __forceinline__ u16 f2b(float v) {          // f32 -> bf16 (RNE)
  unsigned x = __builtin_bit_cast(unsigned, v);
  unsigned r = (x + 0x7fffu + ((x >> 16) & 1u)) >> 16;
  return (u16)r;
}
__device__ __forceinline__ float b2f(u16 u) {
  unsigned x = ((unsigned)u) << 16;
  return __builtin_bit_cast(float, x);
}
// pack two f32 -> one u32 of 2xbf16 (lo -> bits[15:0]), RNE
__device__ __forceinline__ u32 cvtpk(float lo, float hi) {
  u32 r;
  asm("v_cvt_pk_bf16_f32 %0, %1, %2" : "=v"(r) : "v"(lo), "v"(hi));
  return r;
}
// swap lanes[32:63] of a with lanes[0:31] of b (gfx950)
__device__ __forceinline__ void pswap(u32& a, u32& b) {
  asm volatile("v_permlane32_swap_b32 %0, %1" : "+v"(a), "+v"(b));
}
__device__ __forceinline__ f32x4 mfma16(bf16x8 a, bf16x8 b, f32x4 c) {
  return __builtin_amdgcn_mfma_f32_16x16x32_bf16(a, b, c, 0, 0, 0);
}
__device__ __forceinline__ f32x16 mfma32(bf16x8 a, bf16x8 b, f32x16 c) {
  return __builtin_amdgcn_mfma_f32_32x32x16_bf16(a, b, c, 0, 0, 0);
}
__device__ __forceinline__ bf16x8 frag_ld(const u16* p) {
  return __builtin_bit_cast(bf16x8, *(const s16x8*)p);
}
__device__ __forceinline__ void stout(float* p, float v) { *p = v; }
__device__ __forceinline__ void stout(u16*   p, float v) { *p = f2b(v); }

// async global->LDS, 16B per lane. ldsDst is wave-uniform base.
__device__ __forceinline__ void gl_lds16(const void* gSrc, void* ldsDst) {
  __builtin_amdgcn_global_load_lds(
      (const __attribute__((address_space(1))) void*)gSrc,
      (__attribute__((address_space(3))) void*)ldsDst, 16, 0, 0);
}

// ------- merged prep: input LayerNorms (bf16 out) + weight transposes -------
__global__ __launch_bounds__(256) void prep_kernel(
    const float* __restrict__ x,   const float* __restrict__ ln_g,
    const float* __restrict__ ln_b, u16* __restrict__ xn,
    const float* __restrict__ ctx, const float* __restrict__ cln_g,
    const float* __restrict__ cln_b, u16* __restrict__ ctxn,
    const float* __restrict__ Wq, const float* __restrict__ Wkv,
    const float* __restrict__ Wc, const float* __restrict__ Wo,
    u16* __restrict__ WqkvT, u16* __restrict__ WcT, u16* __restrict__ WoT) {
  const int tid = threadIdx.x;
  if (blockIdx.x < Bq * Nq + Bq * Mq) {
    const int row = blockIdx.x;
    const float* in; const float* g; const float* bb; u16* out; int D;
    if (row < Bq * Nq) {
      in = x + (size_t)row * Dq; g = ln_g; bb = ln_b;
      out = xn + (size_t)row * Dq; D = Dq;
    } else {
      int r2 = row - Bq * Nq;
      in = ctx + (size_t)r2 * CDq; g = cln_g; bb = cln_b;
      out = ctxn + (size_t)r2 * CDq; D = CDq;
    }
    __shared__ float buf[1024];
    __shared__ float red[8];
    float s = 0.f, s2 = 0.f;
    for (int i = tid; i < D; i += 256) {
      float v = in[i];
      buf[i] = v;
      s += v; s2 += v * v;
    }
    #pragma unroll
    for (int off = 32; off; off >>= 1) {
      s  += __shfl_down(s,  off);
      s2 += __shfl_down(s2, off);
    }
    if ((tid & 63) == 0) { red[tid >> 6] = s; red[4 + (tid >> 6)] = s2; }
    __syncthreads();
    float sum = red[0] + red[1] + red[2] + red[3];
    float sq  = red[4] + red[5] + red[6] + red[7];
    float mean = sum / D;
    float var  = sq / D - mean * mean;
    float rstd = rsqrtf(var + 1e-5f);
    for (int i = tid; i < D; i += 256)
      out[i] = f2b((buf[i] - mean) * rstd * g[i] + bb[i]);
  } else {
    __shared__ float T[32][33];
    int bid = blockIdx.x - (Bq * Nq + Bq * Mq);
    const float* W; u16* WT; int K, N, bx, by;
    if (bid < 512)      { W = Wq;  WT = WqkvT;                    K = 1024; N = 512;  bx = bid % 16;        by = bid / 16; }
    else if (bid < 640) { W = Wkv; WT = WqkvT + (size_t)512*1024; K = 1024; N = 128;  bx = (bid-512) % 4;   by = (bid-512) / 4; }
    else if (bid < 736) { W = Wc;  WT = WcT;                      K = 768;  N = 128;  bx = (bid-640) % 4;   by = (bid-640) / 4; }
    else                { W = Wo;  WT = WoT;                      K = 512;  N = 1024; bx = (bid-736) % 32;  by = (bid-736) / 32; }
    const int n0 = bx * 32, k0 = by * 32;
    const int tx = tid & 31, ty = tid >> 5;
    #pragma unroll
    for (int i = 0; i < 32; i += 8)
      T[ty + i][tx] = W[(size_t)(k0 + ty + i) * N + n0 + tx];
    __syncthreads();
    #pragma unroll
    for (int i = 0; i < 32; i += 8)
      WT[(size_t)(n0 + ty + i) * K + k0 + tx] = f2b(T[tx][ty + i]);
  }
}

// ---------------- final LayerNorm (bf16 in, fp32 out) ----------------
__global__ __launch_bounds__(256) void ln_out_kernel(
    const u16* __restrict__ in, const float* __restrict__ g,
    const float* __restrict__ bb, float* __restrict__ out) {
  const int row = blockIdx.x;
  const int tid = threadIdx.x;
  __shared__ float buf[1024];
  __shared__ float red[8];
  const u16* xr = in + (size_t)row * Dq;
  float s = 0.f, s2 = 0.f;
  {
    s16x4 v4 = *(const s16x4*)(xr + tid * 4);
    #pragma unroll
    for (int e = 0; e < 4; ++e) {
      float v = b2f((u16)v4[e]);
      buf[tid * 4 + e] = v;
      s += v; s2 += v * v;
    }
  }
  #pragma unroll
  for (int off = 32; off; off >>= 1) {
    s  += __shfl_down(s,  off);
    s2 += __shfl_down(s2, off);
  }
  if ((tid & 63) == 0) { red[tid >> 6] = s; red[4 + (tid >> 6)] = s2; }
  __syncthreads();
  float sum = red[0] + red[1] + red[2] + red[3];
  float sq  = red[4] + red[5] + red[6] + red[7];
  float mean = sum / Dq;
  float var  = sq / Dq - mean * mean;
  float rstd = rsqrtf(var + 1e-5f);
  #pragma unroll
  for (int e = 0; e < 4; ++e) {
    int i = tid * 4 + e;
    out[(size_t)row * Dq + i] = (buf[i] - mean) * rstd * g[i] + bb[i];
  }
}

// ---------- GEMM body (m97 structure), shared by both GEMM kernels ----------
template <typename OT>
__device__ __forceinline__ void gemm_body(const u16* __restrict__ A,
                                          const u16* __restrict__ BT,
                                          OT* __restrict__ C,
                                          int N, int K, int m0, int n0,
                                          u16* Al, u16* Bl) {
  const int tid  = threadIdx.x;
  const int lane = tid & 63, wave = tid >> 6;
  const int l16  = lane & 15, lhi = lane >> 4;
  const int wm = (wave >> 1) * 64, wn = (wave & 1) * 64;

  const int offB = (wave << 10) + (lane << 4);
  const int srow = offB >> 6;
  const int scby = offB & 63;

  f32x4 acc[4][4];
  #pragma unroll
  for (int i = 0; i < 4; ++i)
    #pragma unroll
    for (int j = 0; j < 4; ++j) acc[i][j] = f32x4{0.f, 0.f, 0.f, 0.f};

  for (int k0 = 0; k0 < K; k0 += 32) {
    __syncthreads();
    #pragma unroll
    for (int c = 0; c < 2; ++c) {
      gl_lds16((const char*)(A  + (size_t)(m0 + srow + c * 64) * K + k0) + scby,
               (char*)Al + c * 4096 + (wave << 10));
      gl_lds16((const char*)(BT + (size_t)(n0 + srow + c * 64) * K + k0) + scby,
               (char*)Bl + c * 4096 + (wave << 10));
    }
    __syncthreads();

    bf16x8 af[4], bfr[4];
    #pragma unroll
    for (int mt = 0; mt < 4; ++mt)
      af[mt] = frag_ld(Al + (wm + mt * 16 + l16) * 32 + lhi * 8);
    #pragma unroll
    for (int nt = 0; nt < 4; ++nt)
      bfr[nt] = frag_ld(Bl + (wn + nt * 16 + l16) * 32 + lhi * 8);
    __builtin_amdgcn_s_setprio(1);
    #pragma unroll
    for (int mt = 0; mt < 4; ++mt)
      #pragma unroll
      for (int nt = 0; nt < 4; ++nt)
        acc[mt][nt] = mfma16(af[mt], bfr[nt], acc[mt][nt]);
    __builtin_amdgcn_s_setprio(0);
  }

  #pragma unroll
  for (int mt = 0; mt < 4; ++mt)
    #pragma unroll
    for (int nt = 0; nt < 4; ++nt)
      #pragma unroll
      for (int r = 0; r < 4; ++r)
        stout(C + (size_t)(m0 + wm + mt * 16 + lhi * 4 + r) * N
                + (n0 + wn + nt * 16 + l16),
              acc[mt][nt][r]);
}

// qkv GEMM (y<5) with ckv GEMM folded in as grid row y==5 (8 blocks active)
__global__ __launch_bounds__(256) void gemm_qkv_ckv(
    const u16* __restrict__ xn, const u16* __restrict__ WqkvT,
    u16* __restrict__ qkv,
    const u16* __restrict__ ctxn, const u16* __restrict__ WcT,
    u16* __restrict__ ckvb) {
  const u16 *A, *BT; u16* C; int N, K, m0, n0;
  if (blockIdx.y < 5) {
    A = xn; BT = WqkvT; C = qkv; N = QKVN; K = Dq;
    m0 = blockIdx.x * 128; n0 = blockIdx.y * 128;
  } else {
    if (blockIdx.x >= 8) return;
    A = ctxn; BT = WcT; C = ckvb; N = 2 * DHq; K = CDq;
    m0 = blockIdx.x * 128; n0 = 0;
  }
  __shared__ __align__(16) u16 Al[128 * 32];
  __shared__ __align__(16) u16 Bl[128 * 32];
  gemm_body<u16>(A, BT, C, N, K, m0, n0, Al, Bl);
}

// output projection GEMM (bf16 C = y)
__global__ __launch_bounds__(256) void gemm128b(const u16* __restrict__ A,
                                                const u16* __restrict__ BT,
                                                u16* __restrict__ C,
                                                int N, int K) {
  __shared__ __align__(16) u16 Al[128 * 32];
  __shared__ __align__(16) u16 Bl[128 * 32];
  gemm_body<u16>(A, BT, C, N, K, blockIdx.x * 128, blockIdx.y * 128, Al, Bl);
}

// ------- build tiled+swizzled K / V^T (per (b,chunk): 64x64 bf16 tile) ------
// K tile byte  = row*128 + ((d*2)   ^ ((row&7)<<4))   [row = j within chunk]
// VT tile byte = d*128   + ((row*2) ^ ((d&7)<<4))
__global__ void build_kv(const u16* __restrict__ qkv,   // (B*N,640) bf16
                         const u16* __restrict__ ckvb,  // (B*M,128) bf16
                         const float* __restrict__ nullkv, // (2,64) f32
                         const float* __restrict__ bc,     // (128,) f32
                         u16* __restrict__ Kt, u16* __restrict__ Vt) {
  int idx = blockIdx.x * 256 + threadIdx.x;
  if (idx >= Bq * J2 * 64) return;
  int d = idx & 63;
  int t = idx >> 6;
  int j = t % J2;
  int b = t / J2;
  float k = 0.f, v = 0.f;
  if (j < Mq) {
    const u16* p = ckvb + (size_t)(b * Mq + j) * 128;
    k = b2f(p[d])      + bc[d];
    v = b2f(p[64 + d]) + bc[64 + d];
  } else if (j == Mq) {
    k = nullkv[d];
    v = nullkv[64 + d];
  } else if (j < Jq) {
    const u16* p = qkv + (size_t)(b * Nq + (j - Mq - 1)) * QKVN + 512;
    k = b2f(p[d]);
    v = b2f(p[64 + d]);
  }
  int ch = j >> 6, row = j & 63;
  char* tbase = (char*)Kt + ((size_t)(b * NCH + ch)) * 8192;
  *(u16*)(tbase + row * 128 + ((d << 1) ^ ((row & 7) << 4))) = f2b(k);
  char* vbase = (char*)Vt + ((size_t)(b * NCH + ch)) * 8192;
  *(u16*)(vbase + d * 128 + ((row << 1) ^ ((d & 7) << 4))) = f2b(v);
}

// --- attention: ALL-HEADS blocks -- K/V staged ONCE for 8 heads -------------
// grid (N/32, 1, B) = (64,1,4) = 256 blocks = 1/CU. Block = 512 thr = 8 waves;
// wave w handles head h=w over the SAME 32 q-rows. K/V (head-independent!) is
// staged once per chunk and consumed by all 8 waves: K/V:bias L2 traffic
// ratio drops 1.0 -> 0.25 (-450 MB L2 traffic vs QROWS=64 blocks).
// 32x32 swapped-MFMA, in-register P (permlane32_swap). LDS = 32 KB.
__global__ __launch_bounds__(512) void attn_kernel(
    const u16* __restrict__ qkv, const u16* __restrict__ Kt,
    const u16* __restrict__ Vt, const float* __restrict__ bias,
    u16* __restrict__ att) {
  __shared__ __align__(16) u16 Kl [2][4096];   // [buf][8KB], shared by block
  __shared__ __align__(16) u16 VTl[2][4096];
  const int tid  = threadIdx.x;
  const int wave = tid >> 6, lane = tid & 63;   // wave = head
  const int l = lane & 31, hi = lane >> 5;
  const int qt = blockIdx.x, b = blockIdx.z;
  const int h = wave;
  const int qrow0 = qt * 32;

  // Q B-frags: lane holds Q[q=qrow0+l][d = kt*16 + hi*8 + e], kt=0..3
  bf16x8 qf[4];
  {
    const u16* qp = qkv + ((size_t)(b * Nq + qrow0 + l)) * QKVN
                        + h * DHq + hi * 8;
    #pragma unroll
    for (int kt = 0; kt < 4; ++kt) qf[kt] = frag_ld(qp + kt * 16);
  }

  float m_s = -INFINITY, l_s = 0.f;
  f32x16 oacc[2];   // O[q=(r&3)+8(r>>2)+4hi][d = dt*32 + l]
  #pragma unroll
  for (int dt = 0; dt < 2; ++dt)
    #pragma unroll
    for (int r = 0; r < 16; ++r) oacc[dt][r] = 0.f;

  // bias row base for (b,h,q=qrow0+l), plus the +4*hi column offset
  const float* bp = bias
      + ((size_t)((b * Hq + h) * (size_t)Nq + qrow0 + l)) * Jq + 4 * hi;

  const size_t tb0 = (size_t)b * NCH;
  // staging: wave w covers bytes [w*1024, w*1024+1024) of each 8KB tile
  const int soff = (wave << 10) + (lane << 4);

  auto stage = [&](int buf, int ch) {
    const char* kt_ = (const char*)Kt + (tb0 + ch) * 8192 + soff;
    const char* vt_ = (const char*)Vt + (tb0 + ch) * 8192 + soff;
    gl_lds16(kt_, (char*)&Kl[buf][0]  + (wave << 10));
    gl_lds16(vt_, (char*)&VTl[buf][0] + (wave << 10));
  };

  // bias regs: bv[jt][g] = bias[q][jc + jt*32 + 8g + 4hi + (0..3)]
  auto loadBias = [&](f32x4 (&bv)[2][4], int ch) {
    const int jc = ch * 64;
    if (ch < NCH - 1) {
      #pragma unroll
      for (int jt = 0; jt < 2; ++jt)
        #pragma unroll
        for (int g = 0; g < 4; ++g)
          bv[jt][g] = (f32x4)(*(const f32x4u*)(bp + jc + jt * 32 + 8 * g));
    } else {
      #pragma unroll
      for (int jt = 0; jt < 2; ++jt)
        #pragma unroll
        for (int g = 0; g < 4; ++g)
          #pragma unroll
          for (int e = 0; e < 4; ++e) {
            int jg = jc + jt * 32 + 8 * g + 4 * hi + e;
            bv[jt][g][e] = (jg < Jq) ? bp[jc + jt * 32 + 8 * g + e] : -1e30f;
          }
    }
  };

  f32x4 bvA[2][4], bvB[2][4];
  stage(0, 0);
  loadBias(bvA, 0);
  __syncthreads();

  auto body = [&](int ch, f32x4 (&bvC)[2][4], f32x4 (&bvN)[2][4]) {
    const int cur = ch & 1;
    if (ch + 1 < NCH) {
      stage(cur ^ 1, ch + 1);
      loadBias(bvN, ch + 1);
    }
    const char* kbase = (const char*)&Kl[cur][0];
    const char* vbase = (const char*)&VTl[cur][0];

    // ---- S^T = K @ Q^T (in-place sacc; refcheck'd R9 body) ----
    f32x16 sacc[2];
    #pragma unroll
    for (int jt = 0; jt < 2; ++jt)
      #pragma unroll
      for (int r = 0; r < 16; ++r) sacc[jt][r] = 0.f;
    __builtin_amdgcn_s_setprio(1);
    #pragma unroll
    for (int jt = 0; jt < 2; ++jt) {
      const int row = jt * 32 + l;
      const int sw = (row & 7) << 4;
      #pragma unroll
      for (int kt = 0; kt < 4; ++kt) {
        bf16x8 kf = frag_ld((const u16*)(kbase + row * 128
                                         + ((kt * 32 + hi * 16) ^ sw)));
        sacc[jt] = mfma32(kf, qf[kt], sacc[jt]);
      }
    }
    __builtin_amdgcn_s_setprio(0);

    // ---- scale + bias (in place) ----
    #pragma unroll
    for (int jt = 0; jt < 2; ++jt)
      #pragma unroll
      for (int r = 0; r < 16; ++r)
        sacc[jt][r] = sacc[jt][r] * 0.125f + bvC[jt][r >> 2][r & 3];

    // ---- row max (q = l, dup across hi) ----
    float pmax = sacc[0][0];
    #pragma unroll
    for (int jt = 0; jt < 2; ++jt)
      #pragma unroll
      for (int r = 0; r < 16; ++r) pmax = fmaxf(pmax, sacc[jt][r]);
    pmax = fmaxf(pmax, __shfl_xor(pmax, 32));

    // ---- defer-max rescale ----
    if (__any(pmax > m_s + 8.f)) {
      float mnew = fmaxf(m_s, pmax);
      float corr = __expf(m_s - mnew);
      l_s *= corr;
      m_s = mnew;
      #pragma unroll
      for (int r = 0; r < 16; ++r) {
        float c = __shfl(corr, (r & 3) + 8 * (r >> 2) + 4 * hi);
        oacc[0][r] *= c;
        oacc[1][r] *= c;
      }
    }

    // ---- P = exp(S - m), row sum (in place) ----
    float ps = 0.f;
    #pragma unroll
    for (int jt = 0; jt < 2; ++jt)
      #pragma unroll
      for (int r = 0; r < 16; ++r) {
        float pv = __expf(sacc[jt][r] - m_s);
        sacc[jt][r] = pv;
        ps += pv;
      }
    ps += __shfl_xor(ps, 32);
    l_s += ps;

    // ---- pack P to bf16 pairs ----
    u32 pk[2][8];
    #pragma unroll
    for (int jt = 0; jt < 2; ++jt)
      #pragma unroll
      for (int g = 0; g < 4; ++g) {
        pk[jt][2 * g]     = cvtpk(sacc[jt][4 * g],     sacc[jt][4 * g + 1]);
        pk[jt][2 * g + 1] = cvtpk(sacc[jt][4 * g + 2], sacc[jt][4 * g + 3]);
      }

    // ---- PV: A-frag per kt via permlane32_swap; B = V^T frags ----
    #pragma unroll
    for (int kt = 0; kt < 4; ++kt) {
      const int t = kt & 1, js = kt >> 1;
      u32 a0 = pk[js][4 * t],     b0 = pk[js][4 * t + 2];
      u32 a1 = pk[js][4 * t + 1], b1 = pk[js][4 * t + 3];
      pswap(a0, b0);
      pswap(a1, b1);
      bf16x8 paf = __builtin_bit_cast(bf16x8, u32x4{a0, a1, b0, b1});
      __builtin_amdgcn_s_setprio(1);
      #pragma unroll
      for (int dt = 0; dt < 2; ++dt) {
        const int vrow = dt * 32 + l;
        bf16x8 vf = frag_ld((const u16*)(vbase + vrow * 128
                     + ((kt * 32 + hi * 16) ^ ((vrow & 7) << 4))));
        oacc[dt] = mfma32(paf, vf, oacc[dt]);
      }
      __builtin_amdgcn_s_setprio(0);
    }
    __syncthreads();   // drains staging vmcnt + all LDS reads of cur
  };

  int ch = 0;
  while (true) {
    body(ch, bvA, bvB);
    if (++ch == NCH) break;
    body(ch, bvB, bvA);
    if (++ch == NCH) break;
  }

  // ---- epilogue: 1/l broadcast from lane q to O-layout, store ----
  float linv = 1.0f / l_s;
  #pragma unroll
  for (int r = 0; r < 16; ++r) {
    const int qo = (r & 3) + 8 * (r >> 2) + 4 * hi;
    float inv = __shfl(linv, qo);
    u16* op = att + ((size_t)(b * Nq + qrow0 + qo)) * (Hq * DHq) + h * DHq + l;
    op[0]  = f2b(oacc[0][r] * inv);
    op[32] = f2b(oacc[1][r] * inv);
  }
}

// ---------------- host ----------------
extern "C" void kernel_launch(void* const* d_in, const int* in_sizes, int n_in,
                              void* d_out, int out_size, void* d_ws, size_t ws_size,
                              hipStream_t stream) {
  const float* x       = (const float*)d_in[0];
  const float* context = (const float*)d_in[1];
  const float* att_bias= (const float*)d_in[2];
  const float* ln_g    = (const float*)d_in[3];
  const float* ln_b    = (const float*)d_in[4];
  const float* null_kv = (const float*)d_in[5];
  const float* Wq      = (const float*)d_in[6];
  const float* Wkv     = (const float*)d_in[7];
  const float* cln_g   = (const float*)d_in[8];
  const float* cln_b   = (const float*)d_in[9];
  const float* Wc      = (const float*)d_in[10];
  const float* bc      = (const float*)d_in[11];
  const float* Wo      = (const float*)d_in[12];
  const float* oln_g   = (const float*)d_in[13];
  const float* oln_b   = (const float*)d_in[14];
  float* out = (float*)d_out;

  char* p = (char*)d_ws;
  auto alloc = [&](size_t bytes) {
    void* r = (void*)p;
    p += (bytes + 255) & ~(size_t)255;
    return r;
  };
  u16* xn     = (u16*)alloc((size_t)Bq * Nq * Dq * 2);
  u16* ctxn   = (u16*)alloc((size_t)Bq * Mq * CDq * 2);
  u16* WqkvT  = (u16*)alloc((size_t)QKVN * Dq * 2);       // [640][1024]
  u16* WcT    = (u16*)alloc((size_t)2 * DHq * CDq * 2);   // [128][768]
  u16* WoT    = (u16*)alloc((size_t)Dq * Hq * DHq * 2);   // [1024][512]
  u16* qkv    = (u16*)alloc((size_t)Bq * Nq * QKVN * 2);  // fused q|kv
  u16* ckvb   = (u16*)alloc((size_t)Bq * Mq * 2 * DHq * 2);
  u16* Ktil   = (u16*)alloc((size_t)Bq * NCH * 8192);
  u16* Vtil   = (u16*)alloc((size_t)Bq * NCH * 8192);
  u16* attb   = (u16*)alloc((size_t)Bq * Nq * Hq * DHq * 2);
  u16* y      = (u16*)alloc((size_t)Bq * Nq * Dq * 2);    // bf16 intermediate

  // 1. merged input LNs + weight transposes
  prep_kernel<<<Bq * Nq + Bq * Mq + 1248, 256, 0, stream>>>(
      x, ln_g, ln_b, xn, context, cln_g, cln_b, ctxn,
      Wq, Wkv, Wc, Wo, WqkvT, WcT, WoT);

  // 2. projections: fused q|kv GEMM with ckv GEMM folded in
  gemm_qkv_ckv<<<dim3(Bq * Nq / 128, 6), 256, 0, stream>>>(
      xn, WqkvT, qkv, ctxn, WcT, ckvb);

  // 3. concat K/V into swizzled 64-row tiles
  build_kv<<<(Bq * J2 * 64 + 255) / 256, 256, 0, stream>>>(
      qkv, ckvb, null_kv, bc, Ktil, Vtil);

  // 4. attention (all-heads blocks: K/V staged once per 8 heads)
  attn_kernel<<<dim3(Nq / 32, 1, Bq), 512, 0, stream>>>(
      qkv, Ktil, Vtil, att_bias, attb);

  // 5. output projection (bf16 y) + final LN
  gemm128b<<<dim3(Bq * Nq / 128, Dq / 128), 256, 0, stream>>>(
      attb, WoT, y, Dq, Hq * DHq);
  ln_out_kernel<<<Bq * Nq, 256, 0, stream>>>(y, oln_g, oln_b, out);
}